// Round 21
// baseline (23.713 us; speedup 1.0000x reference)
//
#include <hip/hip_runtime.h>

// CfdInterpolateMeshToGrid: B=8, M=8192 mesh pts/batch, G=2048 grid pts/batch,
// D=2, C=64, K=3.  out[g,c] = sum_k w_k * x[nn_k(g), c] / sum_k w_k,
// w_k = 1 / max(d2_k, 1e-16), d2 = (g2 + m2) - 2*dot.
//
// NUMERICS (locked by rounds 1-5 — DO NOT CHANGE):
//   #pragma clang fp contract(off), plus exactly:
//     m2  = (mx*mx) + (my*my)           // unfused
//     g2  = (gx*gx) + (gy*gy)           // unfused
//     p0  = gx*mx; dot = fmaf(gy,my,p0) // fma-ascending k-contraction (BLAS)
//     t   = g2 + m2
//     d2  = fmaf(-2, dot, t)            // == t - (2*dot) bit-exactly
//   Selection = 3 lex-smallest (d2, idx) — identical to stable top_k and
//   visit-order independent (bin-internal order is irrelevant).
//
// SCHEDULE (round 21): r20's remaining budget is ~5-6us in bin_all, which
// runs its whole serial phase chain on 8 of 256 CUs. Replace with a
// two-level counting sort at 64-block parallelism:
//   bin_hist   (64 blk): per-(batch,subchunk) LDS histogram -> hist2, no
//                        global atomics, no pre-zero;
//   bin_scan   ( 8 blk): bin totals + exclusive scan -> starts; per-sub
//                        bases base2[b][s][bin];
//   bin_scatter(64 blk): LDS cursor from base2, packed float4 write
//                        (locked unfused m2).
// knn_search unchanged from r20 (merge network + XCD-batch affinity).

#define BLK 256
#define LPG 32           // lanes per grid point
#define PPB 8            // grid points per search block (BLK/LPG)
#define NTB 1024
#define NSUB 8           // sub-chunks per batch (M / NTB)
#define NB 32
#define NBINS (NB * NB)
#define PADIDX 0x7FFFFFFF
#define MARGIN 1e-4f

// 64 blocks: block = (batch b, sub s). LDS histogram of own 1024 points.
__global__ void bin_hist(const float* __restrict__ mesh_pos,
                         int* __restrict__ hist2, int M)
{
    __shared__ int h[NBINS];
    const int blk = blockIdx.x;
    const int b = blk >> 3, s = blk & 7;
    const int t = threadIdx.x;
    h[t] = 0;
    __syncthreads();
    const float2 p = ((const float2*)mesh_pos)[(size_t)b * M + s * NTB + t];
    const int bx = max(0, min((int)(p.x * (float)NB), NB - 1));
    const int by = max(0, min((int)(p.y * (float)NB), NB - 1));
    atomicAdd(&h[by * NB + bx], 1);
    __syncthreads();
    hist2[(blk << 10) + t] = h[t];
}

// 8 blocks (one per batch): bin totals, exclusive scan -> starts;
// per-sub bases base2[b][s][bin] = starts[bin] + prefix over subs.
__global__ void bin_scan(const int* __restrict__ hist2,
                         int* __restrict__ starts,   // [B][NBINS+1]
                         int* __restrict__ base2)    // [B][NSUB][NBINS]
{
    __shared__ int wsum[16];
    __shared__ int woff[17];
    const int b = blockIdx.x, t = threadIdx.x;
    int hv[NSUB];
    int tot = 0;
    #pragma unroll
    for (int s = 0; s < NSUB; ++s) {
        hv[s] = hist2[((b * NSUB + s) << 10) + t];
        tot += hv[s];
    }
    int sc = tot;                     // wave-inclusive scan
    #pragma unroll
    for (int off = 1; off < 64; off <<= 1) {
        int nv = __shfl_up(sc, off, 64);
        if ((t & 63) >= off) sc += nv;
    }
    if ((t & 63) == 63) wsum[t >> 6] = sc;
    __syncthreads();
    if (t == 0) {
        int acc = 0;
        #pragma unroll
        for (int i = 0; i < 16; ++i) { woff[i] = acc; acc += wsum[i]; }
        woff[16] = acc;
    }
    __syncthreads();
    const int excl = woff[t >> 6] + sc - tot;
    starts[b * (NBINS + 1) + t] = excl;
    if (t == 0) starts[b * (NBINS + 1) + NBINS] = woff[16];   // = M
    int run = excl;
    #pragma unroll
    for (int s = 0; s < NSUB; ++s) {
        base2[((b * NSUB + s) << 10) + t] = run;
        run += hv[s];
    }
}

// 64 blocks: block = (batch b, sub s). LDS cursor from base2; packed write.
__global__ void bin_scatter(const float* __restrict__ mesh_pos,
                            const int* __restrict__ base2,
                            float4* __restrict__ sxyi,   // (x, y, m2, idx)
                            int M)
{
#pragma clang fp contract(off)
    __shared__ int cur[NBINS];
    const int blk = blockIdx.x;
    const int b = blk >> 3, s = blk & 7;
    const int t = threadIdx.x;
    cur[t] = base2[(blk << 10) + t];
    __syncthreads();
    const int n = s * NTB + t;                         // batch-local index
    const float2 p = ((const float2*)mesh_pos)[(size_t)b * M + n];
    const int bx = max(0, min((int)(p.x * (float)NB), NB - 1));
    const int by = max(0, min((int)(p.y * (float)NB), NB - 1));
    const float m2 = (p.x * p.x) + (p.y * p.y);        // unfused (contract off)
    const int pos = atomicAdd(&cur[by * NB + bx], 1);
    sxyi[(size_t)b * M + pos] = make_float4(p.x, p.y, m2, __int_as_float(n));
}

// lex-(d2, idx) sorted-3 insert; visit-order independent == stable top_k.
#define LEX_INSERT(d2, idx)                                                  \
    if ((d2) < t2 || ((d2) == t2 && (idx) < i2)) {                           \
        if ((d2) < t1 || ((d2) == t1 && (idx) < i1)) {                       \
            t2 = t1; i2 = i1;                                                \
            if ((d2) < t0 || ((d2) == t0 && (idx) < i0)) {                   \
                t1 = t0; i1 = i0; t0 = (d2); i0 = (idx);                     \
            } else { t1 = (d2); i1 = (idx); }                                \
        } else { t2 = (d2); i2 = (idx); }                                    \
    }

// One butterfly level of the sorted-3 merge network: exchange sorted-3 with
// XOR partner, keep lex-3-smallest of the union (exact merge identity).
#define MERGE3_LEVEL(off)                                                    \
    {                                                                        \
        const float o0 = __shfl_xor(t0, (off), 64);                          \
        const int   p0_ = __shfl_xor(i0, (off), 64);                         \
        const float o1 = __shfl_xor(t1, (off), 64);                          \
        const int   p1_ = __shfl_xor(i1, (off), 64);                         \
        const float o2 = __shfl_xor(t2, (off), 64);                          \
        const int   p2_ = __shfl_xor(i2, (off), 64);                         \
        float c0d, d0d; int c0i, d0i;                                        \
        if (o0 < t0 || (o0 == t0 && p0_ < i0))                               \
             { c0d = o0; c0i = p0_; d0d = t0; d0i = i0; }                    \
        else { c0d = t0; c0i = i0; d0d = o0; d0i = p0_; }                    \
        float c1d; int c1i;                                                  \
        if (o1 < t1 || (o1 == t1 && p1_ < i1)) { c1d = o1; c1i = p1_; }      \
        else                                   { c1d = t1; c1i = i1; }      \
        float c2d; int c2i;                                                  \
        if (o2 < t2 || (o2 == t2 && p2_ < i2)) { c2d = o2; c2i = p2_; }      \
        else                                   { c2d = t2; c2i = i2; }      \
        float r1d, l1d; int r1i, l1i;                                        \
        if (c1d < d0d || (c1d == d0d && c1i < d0i))                          \
             { r1d = c1d; r1i = c1i; l1d = d0d; l1i = d0i; }                 \
        else { r1d = d0d; r1i = d0i; l1d = c1d; l1i = c1i; }                 \
        float r2d; int r2i;                                                  \
        if (c2d < l1d || (c2d == l1d && c2i < l1i)) { r2d = c2d; r2i = c2i; }\
        else                                        { r2d = l1d; r2i = l1i; }\
        t0 = c0d; i0 = c0i; t1 = r1d; i1 = r1i; t2 = r2d; i2 = r2i;          \
    }

// Search: block = 8 grid points, 32 lanes each; 2048 blocks, XCD-batch
// affinity swizzle. Flat ring scan, merge-network reduce, fused gather.
__global__ void knn_search(const float* __restrict__ x,
                           const float* __restrict__ grid_pos,
                           const float4* __restrict__ sxyi,
                           const int* __restrict__ starts,
                           float* __restrict__ out,
                           int M, int G)
{
#pragma clang fp contract(off)
    const int tid  = threadIdx.x;
    // XCD-batch affinity: batch c's 256 blocks all carry bid%8 == c.
    const int lb   = (blockIdx.x >> 3) + (blockIdx.x & 7) * 256;
    const int g0   = lb * PPB;
    const int b    = g0 / G;              // == blockIdx.x & 7
    const int pt   = tid >> 5;            // block-local point 0..7
    const int li   = tid & (LPG - 1);     // lane within point group
    const int lane = tid & 63;

    const int g = g0 + pt;
    const float2 gp = ((const float2*)grid_pos)[g];   // broadcast in group
    const float gx = gp.x, gy = gp.y;
    const float g2 = (gx * gx) + (gy * gy);           // unfused

    const int gbx = max(0, min((int)(gx * (float)NB), NB - 1));
    const int gby = max(0, min((int)(gy * (float)NB), NB - 1));
    const int bxlo = max(gbx - 1, 0), bxhi = min(gbx + 1, NB - 1);
    const int bylo = max(gby - 1, 0), byhi = min(gby + 1, NB - 1);

    const int* st = starts + b * (NBINS + 1);          // L2-resident (4KB)
    const float4* bxyi = sxyi + (size_t)b * M;

    // Hoist all row bounds (up to 6 loads issued before scanning).
    const int lo0 = st[bylo * NB + bxlo];
    const int hi0 = st[bylo * NB + bxhi + 1];
    int lo1 = 0, hi1 = 0, lo2 = 0, hi2 = 0;
    if (bylo + 1 <= byhi) { lo1 = st[(bylo + 1) * NB + bxlo];
                            hi1 = st[(bylo + 1) * NB + bxhi + 1]; }
    if (bylo + 2 <= byhi) { lo2 = st[(bylo + 2) * NB + bxlo];
                            hi2 = st[(bylo + 2) * NB + bxhi + 1]; }

    // Flatten the 3 segments into one T-length list.
    const int c0  = hi0 - lo0;
    const int c01 = c0 + (hi1 - lo1);
    const int T   = c01 + (hi2 - lo2);

    float t0 = 1e30f, t1 = 1e30f, t2 = 1e30f;
    int   i0 = PADIDX, i1 = PADIDX, i2 = PADIDX;

    for (int L = li; L < T; L += LPG) {
        int sp;
        if (L < c0)       sp = lo0 + L;
        else if (L < c01) sp = lo1 + (L - c0);
        else              sp = lo2 + (L - c01);
        const float4 v = bxyi[sp];
        const float p0  = gx * v.x;
        const float dot = fmaf(gy, v.y, p0);
        const float t   = g2 + v.z;                    // v.z = m2 (bit-exact)
        const float d2  = fmaf(-2.0f, dot, t);
        const int   idx = __float_as_int(v.w);
        LEX_INSERT(d2, idx)
    }

    // 5-level sorted-3 merge network within the 32-lane group.
    MERGE3_LEVEL(1)  MERGE3_LEVEL(2)  MERGE3_LEVEL(4)
    MERGE3_LEVEL(8)  MERGE3_LEVEL(16)
    float wd0 = t0, wd1 = t1, wd2 = t2;
    int   wi0 = i0, wi1 = i1, wi2 = i2;

    // Containment check (group-uniform): distance to unexamined region.
    const float w = 1.0f / (float)NB;
    const float dl = (bxlo > 0)      ? (gx - (float)bxlo * w)       : 1e30f;
    const float dr = (bxhi < NB - 1) ? ((float)(bxhi + 1) * w - gx) : 1e30f;
    const float dn = (bylo > 0)      ? (gy - (float)bylo * w)       : 1e30f;
    const float dt = (byhi < NB - 1) ? ((float)(byhi + 1) * w - gy) : 1e30f;
    const float bdd = fminf(fminf(dl, dr), fminf(dn, dt));
    const float bd2 = bdd * bdd;
    const bool need = (li == 0) && !(wd2 + MARGIN < bd2);

    // Rare fallback: wave-cooperative exact scan (merge network over 64).
    unsigned long long mask = __ballot(need);
    while (mask) {
        const int l = __builtin_ctzll(mask); mask &= mask - 1;
        const int ptf = ((tid & ~63) + l) >> 5;        // block-local point
        const float2 fgp = ((const float2*)grid_pos)[g0 + ptf];
        const float fgx = fgp.x, fgy = fgp.y;
        const float fg2 = (fgx * fgx) + (fgy * fgy);   // unfused
        t0 = 1e30f; t1 = 1e30f; t2 = 1e30f;
        i0 = PADIDX; i1 = PADIDX; i2 = PADIDX;
        for (int j = lane; j < M; j += 64) {
            const float4 v = bxyi[j];
            const float p0  = fgx * v.x;
            const float dot = fmaf(fgy, v.y, p0);
            const float t   = fg2 + v.z;
            const float d2  = fmaf(-2.0f, dot, t);
            const int   idx = __float_as_int(v.w);
            LEX_INSERT(d2, idx)
        }
        MERGE3_LEVEL(1)  MERGE3_LEVEL(2)  MERGE3_LEVEL(4)
        MERGE3_LEVEL(8)  MERGE3_LEVEL(16) MERGE3_LEVEL(32)
        if (pt == ptf) { wd0 = t0; wi0 = i0; wd1 = t1; wi1 = i1;
                         wd2 = t2; wi2 = i2; }
    }

    // Gather: wave handles its own 2 points; results via shuffle broadcast.
    const int wv = tid >> 6;
    const size_t rowBase = (size_t)b * M * 64;
    #pragma unroll
    for (int q = 0; q < 2; ++q) {
        const int src = q << 5;                        // lane q*32 of this wave
        const float a0 = __shfl(wd0, src, 64);
        const float a1 = __shfl(wd1, src, 64);
        const float a2 = __shfl(wd2, src, 64);
        const int   J0 = __shfl(wi0, src, 64);
        const int   J1 = __shfl(wi1, src, 64);
        const int   J2 = __shfl(wi2, src, 64);
        const float W0 = 1.0f / fmaxf(a0, 1e-16f);
        const float W1 = 1.0f / fmaxf(a1, 1e-16f);
        const float W2 = 1.0f / fmaxf(a2, 1e-16f);
        const float x0 = x[rowBase + (size_t)J0 * 64 + lane];
        const float x1 = x[rowBase + (size_t)J1 * 64 + lane];
        const float x2 = x[rowBase + (size_t)J2 * 64 + lane];
        const float num = ((W0 * x0) + (W1 * x1)) + (W2 * x2);  // unfused
        const float den = (W0 + W1) + W2;
        out[(size_t)(g0 + (wv << 1) + q) * 64 + lane] = num / den;
    }
}

extern "C" void kernel_launch(void* const* d_in, const int* in_sizes, int n_in,
                              void* d_out, int out_size, void* d_ws, size_t ws_size,
                              hipStream_t stream) {
    const float* x        = (const float*)d_in[0];
    const float* mesh_pos = (const float*)d_in[1];
    const float* grid_pos = (const float*)d_in[2];
    // d_in[3] = batch_idx (int64) — contiguous repeat layout, unused.

    const int N  = in_sizes[1] / 2;   // 65536
    const int Gt = in_sizes[2] / 2;   // 16384
    const int B  = 8;
    const int M  = N / B;             // 8192
    const int G  = Gt / B;            // 2048

    // Workspace (~1.6 MB): hist2 + base2 + starts + packed candidates.
    char* p = (char*)d_ws;
    int*    hist2  = (int*)p;     p += (size_t)B * NSUB * NBINS * sizeof(int);
    int*    base2  = (int*)p;     p += (size_t)B * NSUB * NBINS * sizeof(int);
    int*    starts = (int*)p;     p += (size_t)B * (NBINS + 1) * sizeof(int);
    float4* sxyi   = (float4*)p;

    bin_hist   <<<B * NSUB, NTB, 0, stream>>>(mesh_pos, hist2, M);
    bin_scan   <<<B, NTB, 0, stream>>>(hist2, starts, base2);
    bin_scatter<<<B * NSUB, NTB, 0, stream>>>(mesh_pos, base2, sxyi, M);
    knn_search <<<Gt / PPB, BLK, 0, stream>>>(x, grid_pos, sxyi, starts,
                                              (float*)d_out, M, G);
}

// Round 22
// 19.601 us; speedup vs baseline: 1.2098x; 1.2098x over previous
//
#include <hip/hip_runtime.h>

// CfdInterpolateMeshToGrid: B=8, M=8192 mesh pts/batch, G=2048 grid pts/batch,
// D=2, C=64, K=3.  out[g,c] = sum_k w_k * x[nn_k(g), c] / sum_k w_k,
// w_k = 1 / max(d2_k, 1e-16), d2 = (g2 + m2) - 2*dot.
//
// NUMERICS (locked by rounds 1-5 — DO NOT CHANGE):
//   #pragma clang fp contract(off), plus exactly:
//     m2  = (mx*mx) + (my*my)           // unfused
//     g2  = (gx*gx) + (gy*gy)           // unfused
//     p0  = gx*mx; dot = fmaf(gy,my,p0) // fma-ascending k-contraction (BLAS)
//     t   = g2 + m2
//     d2  = fmaf(-2, dot, t)            // == t - (2*dot) bit-exactly
//   Selection = 3 lex-smallest (d2, idx) — identical to stable top_k and
//   visit-order independent.
//
// SCHEDULE (round 22): r21's 64-block counting sort REGRESSED (+4us: two
// 256KB global round-trips + 3 shallow kernels; fused bin_all's phases share
// residency and cost only ~2-3us). Revert to r20 (19.6us best) + ONE change:
// the scan loop's serial chain {load->insert->load->insert->load->insert}
// (3 x ~300-600cyc dependent L2/L3 latencies/wave) is chunked — all 3
// candidate loads issue independently (named va/vb/vc, no runtime-indexed
// arrays) BEFORE the inserts: one load latency instead of three. Visit order
// and d2 bits unchanged.

#define BLK 256
#define LPG 32           // lanes per grid point
#define PPB 8            // grid points per search block (BLK/LPG)
#define NTB 1024
#define NB 32
#define NBINS (NB * NB)
#define PADIDX 0x7FFFFFFF
#define MARGIN 1e-4f

// One block per batch: zero + histogram + scan + LDS-staged scatter +
// coalesced write-out of packed candidates (x, y, m2, idx_bits).
__global__ void bin_all(const float* __restrict__ mesh_pos,
                        int* __restrict__ starts,    // [B][NBINS+1]
                        float4* __restrict__ sxyi,
                        int M)
{
#pragma clang fp contract(off)
    __shared__ int h[NBINS];          // histogram, then cursor
    __shared__ int wsum[16];
    __shared__ int woff[17];
    extern __shared__ char dsm[];     // M*12 bytes: staged sorted array
    float2* stage = (float2*)dsm;
    int*    sidl  = (int*)(dsm + (size_t)M * sizeof(float2));

    const int b = blockIdx.x, t = threadIdx.x;

    h[t] = 0;                         // NBINS == NTB == 1024
    __syncthreads();

    const float2* mp = (const float2*)mesh_pos + (size_t)b * M;
    for (int n = t; n < M; n += NTB) {
        const float2 p = mp[n];
        const int bx = max(0, min((int)(p.x * (float)NB), NB - 1));
        const int by = max(0, min((int)(p.y * (float)NB), NB - 1));
        atomicAdd(&h[by * NB + bx], 1);
    }
    __syncthreads();

    const int v = h[t];
    int sc = v;                       // wave-inclusive scan
    #pragma unroll
    for (int off = 1; off < 64; off <<= 1) {
        int nv = __shfl_up(sc, off, 64);
        if ((t & 63) >= off) sc += nv;
    }
    if ((t & 63) == 63) wsum[t >> 6] = sc;
    __syncthreads();
    if (t == 0) {
        int acc = 0;
        #pragma unroll
        for (int i = 0; i < 16; ++i) { woff[i] = acc; acc += wsum[i]; }
        woff[16] = acc;
    }
    __syncthreads();
    const int excl = woff[t >> 6] + sc - v;
    starts[b * (NBINS + 1) + t] = excl;
    if (t == 0) starts[b * (NBINS + 1) + NBINS] = woff[16];   // = M
    __syncthreads();                  // everyone done reading h[t]
    h[t] = excl;                      // cursor
    __syncthreads();

    for (int n = t; n < M; n += NTB) {
        const float2 p = mp[n];       // L1 hit (just streamed)
        const int bx = max(0, min((int)(p.x * (float)NB), NB - 1));
        const int by = max(0, min((int)(p.y * (float)NB), NB - 1));
        const int pos = atomicAdd(&h[by * NB + bx], 1);
        stage[pos] = p;               // LDS scatter (cheap)
        sidl[pos]  = n;               // batch-local index
    }
    __syncthreads();

    // Coalesced write-out; m2 recomputed with the locked unfused expression.
    for (int n = t; n < M; n += NTB) {
        const float2 p = stage[n];
        const float m2 = (p.x * p.x) + (p.y * p.y);   // unfused (contract off)
        sxyi[(size_t)b * M + n] =
            make_float4(p.x, p.y, m2, __int_as_float(sidl[n]));
    }
}

// lex-(d2, idx) sorted-3 insert; visit-order independent == stable top_k.
#define LEX_INSERT(d2, idx)                                                  \
    if ((d2) < t2 || ((d2) == t2 && (idx) < i2)) {                           \
        if ((d2) < t1 || ((d2) == t1 && (idx) < i1)) {                       \
            t2 = t1; i2 = i1;                                                \
            if ((d2) < t0 || ((d2) == t0 && (idx) < i0)) {                   \
                t1 = t0; i1 = i0; t0 = (d2); i0 = (idx);                     \
            } else { t1 = (d2); i1 = (idx); }                                \
        } else { t2 = (d2); i2 = (idx); }                                    \
    }

// Locked d2 from a packed candidate; then lex insert.
#define D2_INSERT(v, L)                                                      \
    {                                                                        \
        const float p0_  = gx * (v).x;                                       \
        const float dot_ = fmaf(gy, (v).y, p0_);                             \
        const float t_   = g2 + (v).z;                                       \
        const float d2_  = fmaf(-2.0f, dot_, t_);                            \
        const int   ix_  = __float_as_int((v).w);                            \
        float d2 = d2_; int idx = ix_; (void)(L);                            \
        LEX_INSERT(d2, idx)                                                  \
    }

// One butterfly level of the sorted-3 merge network: exchange sorted-3 with
// XOR partner, keep lex-3-smallest of the union (exact merge identity).
#define MERGE3_LEVEL(off)                                                    \
    {                                                                        \
        const float o0 = __shfl_xor(t0, (off), 64);                          \
        const int   p0_ = __shfl_xor(i0, (off), 64);                         \
        const float o1 = __shfl_xor(t1, (off), 64);                          \
        const int   p1_ = __shfl_xor(i1, (off), 64);                         \
        const float o2 = __shfl_xor(t2, (off), 64);                          \
        const int   p2_ = __shfl_xor(i2, (off), 64);                         \
        float c0d, d0d; int c0i, d0i;                                        \
        if (o0 < t0 || (o0 == t0 && p0_ < i0))                               \
             { c0d = o0; c0i = p0_; d0d = t0; d0i = i0; }                    \
        else { c0d = t0; c0i = i0; d0d = o0; d0i = p0_; }                    \
        float c1d; int c1i;                                                  \
        if (o1 < t1 || (o1 == t1 && p1_ < i1)) { c1d = o1; c1i = p1_; }      \
        else                                   { c1d = t1; c1i = i1; }      \
        float c2d; int c2i;                                                  \
        if (o2 < t2 || (o2 == t2 && p2_ < i2)) { c2d = o2; c2i = p2_; }      \
        else                                   { c2d = t2; c2i = i2; }      \
        float r1d, l1d; int r1i, l1i;                                        \
        if (c1d < d0d || (c1d == d0d && c1i < d0i))                          \
             { r1d = c1d; r1i = c1i; l1d = d0d; l1i = d0i; }                 \
        else { r1d = d0d; r1i = d0i; l1d = c1d; l1i = c1i; }                 \
        float r2d; int r2i;                                                  \
        if (c2d < l1d || (c2d == l1d && c2i < l1i)) { r2d = c2d; r2i = c2i; }\
        else                                        { r2d = l1d; r2i = l1i; }\
        t0 = c0d; i0 = c0i; t1 = r1d; i1 = r1i; t2 = r2d; i2 = r2i;          \
    }

// Flat-ring segment decode.
#define DECODE(L) ((L) < c0 ? lo0 + (L)                                      \
                  : ((L) < c01 ? lo1 + ((L) - c0) : lo2 + ((L) - c01)))

// Search: block = 8 grid points, 32 lanes each; 2048 blocks, XCD-batch
// affinity swizzle. Chunked scan (3 independent loads before inserts),
// merge-network reduce, fused gather. No LDS, no barriers.
__global__ void knn_search(const float* __restrict__ x,
                           const float* __restrict__ grid_pos,
                           const float4* __restrict__ sxyi,
                           const int* __restrict__ starts,
                           float* __restrict__ out,
                           int M, int G)
{
#pragma clang fp contract(off)
    const int tid  = threadIdx.x;
    // XCD-batch affinity: batch c's 256 blocks all carry bid%8 == c.
    const int lb   = (blockIdx.x >> 3) + (blockIdx.x & 7) * 256;
    const int g0   = lb * PPB;
    const int b    = g0 / G;              // == blockIdx.x & 7
    const int pt   = tid >> 5;            // block-local point 0..7
    const int li   = tid & (LPG - 1);     // lane within point group
    const int lane = tid & 63;

    const int g = g0 + pt;
    const float2 gp = ((const float2*)grid_pos)[g];   // broadcast in group
    const float gx = gp.x, gy = gp.y;
    const float g2 = (gx * gx) + (gy * gy);           // unfused

    const int gbx = max(0, min((int)(gx * (float)NB), NB - 1));
    const int gby = max(0, min((int)(gy * (float)NB), NB - 1));
    const int bxlo = max(gbx - 1, 0), bxhi = min(gbx + 1, NB - 1);
    const int bylo = max(gby - 1, 0), byhi = min(gby + 1, NB - 1);

    const int* st = starts + b * (NBINS + 1);          // L2-resident (4KB)
    const float4* bxyi = sxyi + (size_t)b * M;

    // Hoist all row bounds (up to 6 loads issued before scanning).
    const int lo0 = st[bylo * NB + bxlo];
    const int hi0 = st[bylo * NB + bxhi + 1];
    int lo1 = 0, hi1 = 0, lo2 = 0, hi2 = 0;
    if (bylo + 1 <= byhi) { lo1 = st[(bylo + 1) * NB + bxlo];
                            hi1 = st[(bylo + 1) * NB + bxhi + 1]; }
    if (bylo + 2 <= byhi) { lo2 = st[(bylo + 2) * NB + bxlo];
                            hi2 = st[(bylo + 2) * NB + bxhi + 1]; }

    // Flatten the 3 segments into one T-length list.
    const int c0  = hi0 - lo0;
    const int c01 = c0 + (hi1 - lo1);
    const int T   = c01 + (hi2 - lo2);

    float t0 = 1e30f, t1 = 1e30f, t2 = 1e30f;
    int   i0 = PADIDX, i1 = PADIDX, i2 = PADIDX;

    // Chunked scan: issue up to 3 INDEPENDENT candidate loads, then insert
    // (ascending L — same visit order as r20; lex selection is order-free).
    for (int base = li; base < T; base += 3 * LPG) {
        const int  L1 = base + LPG, L2v = base + 2 * LPG;
        const bool ok1 = (L1 < T), ok2 = (L2v < T);
        const int  sp0 = DECODE(base);
        const int  sp1 = ok1 ? DECODE(L1)  : sp0;
        const int  sp2 = ok2 ? DECODE(L2v) : sp0;
        const float4 va = bxyi[sp0];       // 3 loads issue back-to-back:
        const float4 vb = bxyi[sp1];       // one round-trip latency, not 3
        const float4 vc = bxyi[sp2];
        D2_INSERT(va, base)
        if (ok1) D2_INSERT(vb, L1)
        if (ok2) D2_INSERT(vc, L2v)
    }

    // 5-level sorted-3 merge network within the 32-lane group.
    MERGE3_LEVEL(1)  MERGE3_LEVEL(2)  MERGE3_LEVEL(4)
    MERGE3_LEVEL(8)  MERGE3_LEVEL(16)
    float wd0 = t0, wd1 = t1, wd2 = t2;
    int   wi0 = i0, wi1 = i1, wi2 = i2;

    // Containment check (group-uniform): distance to unexamined region.
    const float w = 1.0f / (float)NB;
    const float dl = (bxlo > 0)      ? (gx - (float)bxlo * w)       : 1e30f;
    const float dr = (bxhi < NB - 1) ? ((float)(bxhi + 1) * w - gx) : 1e30f;
    const float dn = (bylo > 0)      ? (gy - (float)bylo * w)       : 1e30f;
    const float dt = (byhi < NB - 1) ? ((float)(byhi + 1) * w - gy) : 1e30f;
    const float bdd = fminf(fminf(dl, dr), fminf(dn, dt));
    const float bd2 = bdd * bdd;
    const bool need = (li == 0) && !(wd2 + MARGIN < bd2);

    // Rare fallback: wave-cooperative exact scan (merge network over 64).
    unsigned long long mask = __ballot(need);
    while (mask) {
        const int l = __builtin_ctzll(mask); mask &= mask - 1;
        const int ptf = ((tid & ~63) + l) >> 5;        // block-local point
        const float2 fgp = ((const float2*)grid_pos)[g0 + ptf];
        const float fgx = fgp.x, fgy = fgp.y;
        const float fg2 = (fgx * fgx) + (fgy * fgy);   // unfused
        t0 = 1e30f; t1 = 1e30f; t2 = 1e30f;
        i0 = PADIDX; i1 = PADIDX; i2 = PADIDX;
        for (int j = lane; j < M; j += 64) {
            const float4 v = bxyi[j];
            const float p0  = fgx * v.x;
            const float dot = fmaf(fgy, v.y, p0);
            const float t   = fg2 + v.z;
            const float d2  = fmaf(-2.0f, dot, t);
            const int   idx = __float_as_int(v.w);
            LEX_INSERT(d2, idx)
        }
        MERGE3_LEVEL(1)  MERGE3_LEVEL(2)  MERGE3_LEVEL(4)
        MERGE3_LEVEL(8)  MERGE3_LEVEL(16) MERGE3_LEVEL(32)
        if (pt == ptf) { wd0 = t0; wi0 = i0; wd1 = t1; wi1 = i1;
                         wd2 = t2; wi2 = i2; }
    }

    // Gather: wave handles its own 2 points; results via shuffle broadcast.
    const int wv = tid >> 6;
    const size_t rowBase = (size_t)b * M * 64;
    #pragma unroll
    for (int q = 0; q < 2; ++q) {
        const int src = q << 5;                        // lane q*32 of this wave
        const float a0 = __shfl(wd0, src, 64);
        const float a1 = __shfl(wd1, src, 64);
        const float a2 = __shfl(wd2, src, 64);
        const int   J0 = __shfl(wi0, src, 64);
        const int   J1 = __shfl(wi1, src, 64);
        const int   J2 = __shfl(wi2, src, 64);
        const float W0 = 1.0f / fmaxf(a0, 1e-16f);
        const float W1 = 1.0f / fmaxf(a1, 1e-16f);
        const float W2 = 1.0f / fmaxf(a2, 1e-16f);
        const float x0 = x[rowBase + (size_t)J0 * 64 + lane];
        const float x1 = x[rowBase + (size_t)J1 * 64 + lane];
        const float x2 = x[rowBase + (size_t)J2 * 64 + lane];
        const float num = ((W0 * x0) + (W1 * x1)) + (W2 * x2);  // unfused
        const float den = (W0 + W1) + W2;
        out[(size_t)(g0 + (wv << 1) + q) * 64 + lane] = num / den;
    }
}

extern "C" void kernel_launch(void* const* d_in, const int* in_sizes, int n_in,
                              void* d_out, int out_size, void* d_ws, size_t ws_size,
                              hipStream_t stream) {
    const float* x        = (const float*)d_in[0];
    const float* mesh_pos = (const float*)d_in[1];
    const float* grid_pos = (const float*)d_in[2];
    // d_in[3] = batch_idx (int64) — contiguous repeat layout, unused.

    const int N  = in_sizes[1] / 2;   // 65536
    const int Gt = in_sizes[2] / 2;   // 16384
    const int B  = 8;
    const int M  = N / B;             // 8192
    const int G  = Gt / B;            // 2048

    // Workspace (~1.1 MB): starts + packed candidates.
    char* p = (char*)d_ws;
    int*    starts = (int*)p;     p += (size_t)B * (NBINS + 1) * sizeof(int);
    float4* sxyi   = (float4*)p;

    const size_t dsmBytes = (size_t)M * 12;   // 96 KB staged sort
    bin_all   <<<B, NTB, dsmBytes, stream>>>(mesh_pos, starts, sxyi, M);
    knn_search<<<Gt / PPB, BLK, 0, stream>>>(x, grid_pos, sxyi, starts,
                                             (float*)d_out, M, G);
}